// Round 2
// 2407.928 us; speedup vs baseline: 1.2756x; 1.2756x over previous
//
#include <hip/hip_runtime.h>

#define NN 30000
#define EE 480000

// ---------- zero-fill fallback (ws too small diagnostic) ----------
__global__ __launch_bounds__(256) void k_zero(float* __restrict__ out, int n){
  int i = blockIdx.x*256 + threadIdx.x;
  if (i < n) out[i] = 0.f;
}

// ---------- node feature init: fA[N][288] (row0=node_l0, rest 0), hist=0 ----------
__global__ __launch_bounds__(256) void k_init(
    const float* __restrict__ nl0, float* __restrict__ fA, int* __restrict__ hist)
{
  int i = blockIdx.x*256 + threadIdx.x;   // exactly N*288
  int n = i/288; int r2 = i - n*288;
  fA[i] = (r2 < 32) ? nl0[(size_t)n*32 + r2] : 0.f;
  if (i < NN) hist[i] = 0;
}

__global__ __launch_bounds__(256) void k_hist(const int* __restrict__ dst, int* __restrict__ hist){
  int e = blockIdx.x*256 + threadIdx.x;
  if (e < EE) atomicAdd(&hist[dst[e]], 1);
}

// single-block exclusive scan over hist[NN] -> offs, cursor
__global__ void k_scan(const int* __restrict__ hist, int* __restrict__ offs,
                       int* __restrict__ cursor, int n)
{
  __shared__ int sm[1024];
  __shared__ int carry;
  int tid = threadIdx.x;
  if (tid==0) carry = 0;
  __syncthreads();
  for (int base=0; base<n; base+=1024){
    int i = base + tid;
    int v = (i<n)? hist[i] : 0;
    sm[tid] = v; __syncthreads();
    for (int o=1;o<1024;o<<=1){
      int tv = (tid>=o)? sm[tid-o] : 0;
      __syncthreads();
      sm[tid] += tv;
      __syncthreads();
    }
    int cy = carry;
    int excl = sm[tid] - v;
    if (i<n){ offs[i] = cy+excl; cursor[i] = cy+excl; }
    __syncthreads();
    if (tid==1023) carry = cy + sm[1023];
    __syncthreads();
  }
  if (tid==0) offs[n] = carry;
}

__global__ __launch_bounds__(256) void k_scatter(const int* __restrict__ dst,
    int* __restrict__ cursor, int* __restrict__ perm)
{
  int e = blockIdx.x*256 + threadIdx.x;
  if (e >= EE) return;
  int d = dst[e];
  int p = atomicAdd(&cursor[d], 1);
  perm[p] = e;
}

// ---------- per-node q projection ----------
__global__ __launch_bounds__(256) void k_q(const float* __restrict__ f_in,
    const float* __restrict__ Wqf, float* __restrict__ qn)
{
  int t = blockIdx.x*256 + threadIdx.x;   // N*32 exactly
  int n = t>>5, c = t&31;
  const float* f0 = f_in + (size_t)n*288;
  float acc=0.f;
  #pragma unroll
  for (int ci=0;ci<32;ci++) acc = fmaf(f0[ci], Wqf[ci*32+c], acc);
  qn[t] = acc;
}

// ---------- zero agg buffer + den ----------
__global__ __launch_bounds__(256) void k_zeroagg(float* __restrict__ fo, float* __restrict__ den){
  int i = blockIdx.x*256 + threadIdx.x;   // 33750*256 = NN*288 exactly
  fo[i] = 0.f;
  if (i < NN*4) den[i] = 0.f;
}

// ---------- fused edge pass: MLP once per edge, unnormalized-exp segmented agg ----------
// half-wave (32 lanes) = 1 edge, lane c = channel c. Edges in perm (dst-sorted)
// order; per-half register accumulators flushed via atomicAdd on dst change.
// agg holds sum(e^l * m); den holds sum(e^l) per head. Normalization in k_update.
template<int FIRST>
__global__ __launch_bounds__(256) void k_fused(
    const float* __restrict__ pos, const float* __restrict__ ef,
    const int* __restrict__ src, const int* __restrict__ dst,
    const int* __restrict__ perm,
    const float* __restrict__ f_in, const float* __restrict__ qn,
    const float* __restrict__ Wr1g, const float* __restrict__ br1g,
    const float* __restrict__ Wr2g, const float* __restrict__ Wkg,
    float* __restrict__ aggG, float* __restrict__ den)
{
  // W2 packed as [pair k2][ci][c][2] floats: lane stride 8B -> 2-way bank alias (free)
  __shared__ float W2P[8192];   // 32 KB
  __shared__ float WKL[1024];   // 4 KB
  int tid = threadIdx.x;
  for (int t=tid; t<8192; t+=256){
    int k2 = t>>11; int w = t&2047; int ci = w>>6; int r2 = w&63;
    int c0 = r2>>1; int j = r2&1; int k = k2*2+j;
    W2P[t] = (k<7) ? Wr2g[ci*224 + k*32 + c0] : 0.f;
  }
  for (int t=tid; t<1024; t+=256) WKL[t] = Wkg[t];
  __syncthreads();

  int lane = tid & 63;
  int wv   = tid >> 6;
  int c    = lane & 31;
  int half = lane >> 5;
  int hh   = c >> 3;
  int c2   = c*2;
  int base = blockIdx.x*64 + wv*16;      // 7500 blocks * 64 = 480000 exact

  // W1 column cached in registers: h-loop needs zero LDS traffic
  float w1r[33];
  #pragma unroll
  for (int j=0;j<33;j++) w1r[j] = Wr1g[j*32 + c];
  float b1 = br1g[c];

  float A[9];
  #pragma unroll
  for (int j=0;j<9;j++) A[j]=0.f;
  float denA = 0.f;
  int curd = -1;

  #pragma unroll 1
  for (int it=0; it<8; ++it){
    int p = base + it*2 + half;
    int e = perm[p];
    int s = src[e], d = dst[e];
    float px = pos[d*3+0]-pos[s*3+0];
    float py = pos[d*3+1]-pos[s*3+1];
    float pz = pos[d*3+2]-pos[s*3+2];
    float rr = sqrtf(px*px+py*py+pz*pz+1e-8f);
    float inv = 1.f/rr;
    float y1x=px*inv, y1y=py*inv, y1z=pz*inv;
    float y2a=y1x*y1y, y2b=y1y*y1z, y2c=3.f*y1z*y1z-1.f, y2d=y1x*y1z, y2e=y1x*y1x-y1y*y1y;

    // h = relu([r, ef] @ W1 + b1): ef row re-read as broadcast float4 (VMEM, L1-hot)
    const float4* efr = (const float4*)(ef + (size_t)e*32);
    float h = fmaf(rr, w1r[0], b1);
    #pragma unroll
    for (int jb=0;jb<8;jb++){
      float4 v4 = efr[jb];
      h = fmaf(v4.x, w1r[1+jb*4+0], h);
      h = fmaf(v4.y, w1r[1+jb*4+1], h);
      h = fmaf(v4.z, w1r[1+jb*4+2], h);
      h = fmaf(v4.w, w1r[1+jb*4+3], h);
    }
    h = fmaxf(h, 0.f);

    // w = h @ W2 (packed float2 LDS reads; layer0 prunes the f1/f2 weights)
    float w0=0.f,w1=0.f,w2=0.f,w3=0.f,w4=0.f,w5=0.f,w6=0.f;
    #pragma unroll
    for (int ci=0;ci<32;ci++){
      float hb = __shfl(h, ci, 32);
      float2 q0 = *(const float2*)&W2P[       ci*64 + c2];   // w0,w1
      float2 q1 = *(const float2*)&W2P[2048 + ci*64 + c2];   // w2,w3
      float2 q2 = *(const float2*)&W2P[4096 + ci*64 + c2];   // w4,w5
      w0 = fmaf(hb, q0.x, w0);
      w3 = fmaf(hb, q1.y, w3);
      w5 = fmaf(hb, q2.y, w5);
      if (!FIRST){
        float2 q3 = *(const float2*)&W2P[6144 + ci*64 + c2]; // w6,pad
        w1 = fmaf(hb, q0.y, w1);
        w2 = fmaf(hb, q1.x, w2);
        w4 = fmaf(hb, q2.x, w4);
        w6 = fmaf(hb, q3.x, w6);
      }
    }

    const float* fs = f_in + (size_t)s*288;
    float f0v = fs[c];
    float f1a=0.f,f1b=0.f,f1c=0.f,f2a=0.f,f2b=0.f,f2c=0.f,f2d=0.f,f2e=0.f;
    float m0v = w0*f0v;
    if (!FIRST){
      f1a=fs[32+c]; f1b=fs[64+c]; f1c=fs[96+c];
      f2a=fs[128+c]; f2b=fs[160+c]; f2c=fs[192+c]; f2d=fs[224+c]; f2e=fs[256+c];
      m0v += w1*(f1a*y1x+f1b*y1y+f1c*y1z)
           + w2*(f2a*y2a+f2b*y2b+f2c*y2c+f2d*y2d+f2e*y2e);
    }

    // k = m0 @ Wk; logits = sum_head(q*k)/sqrt(8)
    float kk=0.f;
    #pragma unroll
    for (int ci=0;ci<32;ci++){
      float mb = __shfl(m0v, ci, 32);
      kk = fmaf(mb, WKL[ci*32+c], kk);
    }
    float pr = qn[(size_t)d*32 + c] * kk;
    pr += __shfl_xor(pr,1,8);
    pr += __shfl_xor(pr,2,8);
    pr += __shfl_xor(pr,4,8);
    float el = __expf(pr * 0.35355339059327373f);  // unnormalized; logits O(1), no overflow

    if (d != curd){
      if (curd >= 0){
        #pragma unroll
        for (int j=0;j<9;j++) atomicAdd(&aggG[(size_t)curd*288 + j*32 + c], A[j]);
        if ((c&7)==0) atomicAdd(&den[(size_t)curd*4 + hh], denA);
      }
      #pragma unroll
      for (int j=0;j<9;j++) A[j]=0.f;
      denA = 0.f;
      curd = d;
    }
    denA += el;
    A[0] = fmaf(el, m0v, A[0]);
    A[1] = fmaf(el, w3*f0v*y1x + w4*f1a, A[1]);
    A[2] = fmaf(el, w3*f0v*y1y + w4*f1b, A[2]);
    A[3] = fmaf(el, w3*f0v*y1z + w4*f1c, A[3]);
    A[4] = fmaf(el, w5*f0v*y2a + w6*f2a, A[4]);
    A[5] = fmaf(el, w5*f0v*y2b + w6*f2b, A[5]);
    A[6] = fmaf(el, w5*f0v*y2c + w6*f2c, A[6]);
    A[7] = fmaf(el, w5*f0v*y2d + w6*f2d, A[7]);
    A[8] = fmaf(el, w5*f0v*y2e + w6*f2e, A[8]);
  }
  if (curd >= 0){
    #pragma unroll
    for (int j=0;j<9;j++) atomicAdd(&aggG[(size_t)curd*288 + j*32 + c], A[j]);
    if ((c&7)==0) atomicAdd(&den[(size_t)curd*4 + hh], denA);
  }
}

// ---------- node update: f_out = [(agg0/den)@Ws0 + f0@Wsk, (agg1/den)@Ws1, (agg2/den)@Ws2] ----------
__global__ __launch_bounds__(256) void k_update(
    const float* __restrict__ aggG, const float* __restrict__ f_in,
    const float* __restrict__ den,
    const float* __restrict__ Ws0, const float* __restrict__ Ws1,
    const float* __restrict__ Ws2, const float* __restrict__ Wsk,
    float* __restrict__ f_out)
{
  __shared__ float wL[4096];
  __shared__ float agL[8][297];
  __shared__ float f0L[8][33];
  __shared__ float dL[8][4];
  int tid = threadIdx.x;
  int nb = blockIdx.x*8;
  for (int i=tid;i<1024;i+=256){
    wL[i]=Ws0[i]; wL[1024+i]=Ws1[i]; wL[2048+i]=Ws2[i]; wL[3072+i]=Wsk[i];
  }
  if (tid < 32){
    int nl = tid>>2, hd = tid&3;
    dL[nl][hd] = 1.f/(den[(size_t)(nb+nl)*4 + hd] + 1e-30f);
  }
  { int nl=tid>>5, cc=tid&31; f0L[nl][cc] = f_in[(size_t)(nb+nl)*288 + cc]; }
  __syncthreads();
  for (int i=tid;i<2304;i+=256){
    int nl=i/288, F=i-nl*288, r=F>>5, cc=F&31;
    agL[nl][r*33+cc] = aggG[(size_t)(nb+nl)*288 + F] * dL[nl][cc>>3];
  }
  __syncthreads();
  int nl = tid>>5, o = tid&31;
  size_t obase = (size_t)(nb+nl)*288;
  #pragma unroll 1
  for (int r=0;r<9;r++){
    const float* W = (r==0)? wL : ((r<4)? wL+1024 : wL+2048);
    float acc=0.f;
    #pragma unroll
    for (int cc=0;cc<32;cc++) acc = fmaf(agL[nl][r*33+cc], W[cc*32+o], acc);
    if (r==0){
      #pragma unroll
      for (int cc=0;cc<32;cc++) acc = fmaf(f0L[nl][cc], wL[3072 + cc*32+o], acc);
    }
    f_out[obase + r*32 + o] = acc;
  }
}

// ---------- output head (f32 out) ----------
__global__ __launch_bounds__(256) void k_out(
    const float* __restrict__ f_in, const float* __restrict__ Wout,
    const float* __restrict__ Wc, float* __restrict__ out)
{
  __shared__ float sh[8][33];
  int tid = threadIdx.x;
  int nl = tid>>5, c = tid&31;
  int n = blockIdx.x*8 + nl;
  const float* f0 = f_in + (size_t)n*288;
  float acc=0.f;
  #pragma unroll
  for (int ci=0;ci<32;ci++) acc = fmaf(f0[ci], Wout[ci*32+c], acc);
  out[(size_t)n*32 + c] = acc;
  sh[nl][c] = acc;
  __syncthreads();
  if (tid < 120){
    int nl2 = tid/15, j = tid%15;
    int n2 = blockIdx.x*8 + nl2;
    float a = 0.f;
    #pragma unroll
    for (int ci=0;ci<32;ci++) a = fmaf(sh[nl2][ci], Wc[ci*15+j], a);
    out[(size_t)NN*32 + (size_t)n2*15 + j] = a;
  }
}

extern "C" void kernel_launch(void* const* d_in, const int* in_sizes, int n_in,
                              void* d_out, int out_size, void* d_ws, size_t ws_size,
                              hipStream_t stream)
{
  (void)in_sizes; (void)n_in;
  const float* pos       = (const float*)d_in[0];
  const float* node_l0   = (const float*)d_in[1];
  const float* edge_feat = (const float*)d_in[2];
  const int* esrc = (const int*)d_in[3];
  const int* edst = (const int*)d_in[4];
  const float* Wr1  = (const float*)d_in[5];
  const float* br1  = (const float*)d_in[6];
  const float* Wr2  = (const float*)d_in[7];
  const float* Wq   = (const float*)d_in[8];
  const float* Wk   = (const float*)d_in[9];
  const float* Ws0  = (const float*)d_in[10];
  const float* Ws1  = (const float*)d_in[11];
  const float* Ws2  = (const float*)d_in[12];
  const float* Wsk  = (const float*)d_in[13];
  const float* Wout = (const float*)d_in[14];
  const float* Wc   = (const float*)d_in[15];

  char* ws = (char*)d_ws;
  size_t off = 0;
  auto take = [&](size_t bytes)->char*{
    char* p = ws + off;
    off += (bytes + 255) & ~(size_t)255;
    return p;
  };
  float* fA      = (float*)take((size_t)NN*288*4);   // 34.56 MB
  float* fB      = (float*)take((size_t)NN*288*4);   // 34.56 MB
  float* qn      = (float*)take((size_t)NN*32*4);    //  3.84 MB
  int*   hist    = (int*)  take((size_t)NN*4);
  int*   offs    = (int*)  take((size_t)(NN+1)*4);
  int*   cursor  = (int*)  take((size_t)NN*4);
  int*   perm    = (int*)  take((size_t)EE*4);       //  1.92 MB
  float* den     = (float*)take((size_t)NN*4*4);     //  0.48 MB
  size_t need = off;                                  // ~76 MB (< previous 83 MB, proven OK)

  if (ws_size < need){
    k_zero<<<(out_size+255)/256,256,0,stream>>>((float*)d_out, out_size);
    return;
  }

  k_init<<<33750,256,0,stream>>>(node_l0, fA, hist);
  k_hist<<<1875,256,0,stream>>>(edst, hist);
  k_scan<<<1,1024,0,stream>>>(hist, offs, cursor, NN);
  k_scatter<<<1875,256,0,stream>>>(edst, cursor, perm);

  float* fi = fA; float* fo = fB;
  for (int l=0; l<2; ++l){
    k_zeroagg<<<33750,256,0,stream>>>(fo, den);
    k_q<<<3750,256,0,stream>>>(fi, Wq + l*1024, qn);
    if (l==0){
      k_fused<1><<<7500,256,0,stream>>>(pos, edge_feat, esrc, edst, perm,
          fi, qn, Wr1 + l*1056, br1 + l*32, Wr2 + l*7168, Wk + l*1024,
          fo, den);
    } else {
      k_fused<0><<<7500,256,0,stream>>>(pos, edge_feat, esrc, edst, perm,
          fi, qn, Wr1 + l*1056, br1 + l*32, Wr2 + l*7168, Wk + l*1024,
          fo, den);
    }
    k_update<<<3750,256,0,stream>>>(fo, fi, den,
        Ws0 + l*1024, Ws1 + l*1024, Ws2 + l*1024, Wsk + l*1024, fo);
    float* tmp = fi; fi = fo; fo = tmp;
  }
  k_out<<<3750,256,0,stream>>>(fi, Wout, Wc, (float*)d_out);
}